// Round 9
// baseline (2165.695 us; speedup 1.0000x reference)
//
#include <hip/hip_runtime.h>
#include <stdint.h>

#define N_TOK 8192
#define DIM   2048
#define NEXP  16
#define HID   1408
#define SHID  2816
#define KTOP  4
#define TILEMAX 272   // worst-case routed row-tiles: sum ceil(cnt/128) <= 256+15; 272 = 8*34

typedef __attribute__((ext_vector_type(8))) short bf16x8;
typedef __attribute__((ext_vector_type(4))) float f32x4;

#define MFMA16(a,b,c) __builtin_amdgcn_mfma_f32_16x16x32_bf16((a),(b),(c),0,0,0)

// counted waits (T4): never drain vmcnt to 0 in steady state. lgkmcnt(0) included so any
// compiler-scheduled ds ops are ordered before the barrier. sched_barrier(0) after each
// wait prevents hipcc hoisting ds_read/MFMA above the inline-asm wait (guide rule #18).
#define WAIT_VM(n)  do { asm volatile("s_waitcnt vmcnt(" #n ") lgkmcnt(0)" ::: "memory"); \
                         __builtin_amdgcn_sched_barrier(0); } while(0)
#define WAIT_ALL()  do { asm volatile("s_waitcnt vmcnt(0) lgkmcnt(0)" ::: "memory"); \
                         __builtin_amdgcn_sched_barrier(0); } while(0)
#define BARRIER()   __builtin_amdgcn_s_barrier()

__device__ __forceinline__ unsigned short f2b(float f){
  unsigned u = __float_as_uint(f);
  return (unsigned short)((u + 0x7fffu + ((u >> 16) & 1u)) >> 16);  // RNE bf16
}
__device__ __forceinline__ unsigned pk2(float a, float b){
  return (unsigned)f2b(a) | ((unsigned)f2b(b) << 16);
}
__device__ __forceinline__ float bu2f(unsigned hs){ return __uint_as_float(hs << 16); }
__device__ __forceinline__ float siluf(float x){ return x / (1.f + expf(-x)); }
__device__ __forceinline__ f32x4 zero4(){ f32x4 z; z[0]=0.f; z[1]=0.f; z[2]=0.f; z[3]=0.f; return z; }

// async global->LDS, 16B per lane. LDS dest is wave-uniform base + lane*16 (linear).
__device__ __forceinline__ void gll16(const unsigned short* g, unsigned short* l){
  __builtin_amdgcn_global_load_lds(
      (const __attribute__((address_space(1))) void*)g,
      (__attribute__((address_space(3))) void*)l, 16, 0, 0);
}

// fused 5-tensor weight convert (one launch instead of five)
#define SEGW ((size_t)NEXP*HID*DIM/4)
#define SEGS ((size_t)SHID*DIM/4)
__global__ __launch_bounds__(256) void k_cvtW(const float* __restrict__ W1, const float* __restrict__ W3,
                                              const float* __restrict__ W2, const float* __restrict__ Ws1,
                                              const float* __restrict__ Ws2,
                                              unsigned short* __restrict__ d1, unsigned short* __restrict__ d3,
                                              unsigned short* __restrict__ d2, unsigned short* __restrict__ ds1,
                                              unsigned short* __restrict__ ds2){
  size_t total = 3*SEGW + 2*SEGS;
  for (size_t i = (size_t)blockIdx.x*256 + threadIdx.x; i < total; i += (size_t)gridDim.x*256){
    const float* s; unsigned short* d; size_t off;
    if      (i <   SEGW)        { s = W1;  d = d1;  off = i; }
    else if (i < 2*SEGW)        { s = W3;  d = d3;  off = i - SEGW; }
    else if (i < 3*SEGW)        { s = W2;  d = d2;  off = i - 2*SEGW; }
    else if (i < 3*SEGW + SEGS) { s = Ws1; d = ds1; off = i - 3*SEGW; }
    else                        { s = Ws2; d = ds2; off = i - 3*SEGW - SEGS; }
    float4 v = ((const float4*)s)[off];
    uint2 q; q.x = pk2(v.x, v.y); q.y = pk2(v.z, v.w);
    ((uint2*)d)[off] = q;
  }
}

// ---------------- gate (fused with X->bf16 convert): fp32 logits, softmax, top-4 ----------------
__global__ __launch_bounds__(256) void k_gate(const float* __restrict__ X, const float* __restrict__ Wg,
                                              float* __restrict__ topw, int* __restrict__ topi,
                                              int* __restrict__ cnt, unsigned short* __restrict__ Xb){
  int lane = threadIdx.x & 63;
  int t = blockIdx.x*4 + (threadIdx.x >> 6);
  const float* xr = X + (size_t)t*DIM;
  float4 xv[8];
#pragma unroll
  for (int i=0;i<8;i++){
    xv[i] = *(const float4*)(xr + i*256 + lane*4);
    uint2 q; q.x = pk2(xv[i].x, xv[i].y); q.y = pk2(xv[i].z, xv[i].w);
    *(uint2*)(Xb + (size_t)t*DIM + i*256 + lane*4) = q;   // fused bf16 convert
  }
  float sc[NEXP];
#pragma unroll
  for (int e=0;e<NEXP;e++){
    const float* wr = Wg + e*DIM;
    float s = 0.f;
#pragma unroll
    for (int i=0;i<8;i++){
      float4 w = *(const float4*)(wr + i*256 + lane*4);
      s = fmaf(xv[i].x, w.x, s); s = fmaf(xv[i].y, w.y, s);
      s = fmaf(xv[i].z, w.z, s); s = fmaf(xv[i].w, w.w, s);
    }
#pragma unroll
    for (int d=1; d<64; d<<=1) s += __shfl_xor(s, d);
    sc[e] = s;
  }
  if (lane == 0){
    float m = sc[0];
#pragma unroll
    for (int e=1;e<NEXP;e++) m = fmaxf(m, sc[e]);
    float den = 0.f;
#pragma unroll
    for (int e=0;e<NEXP;e++){ sc[e] = expf(sc[e]-m); den += sc[e]; }
    float inv = 1.f/den;
#pragma unroll
    for (int e=0;e<NEXP;e++) sc[e] *= inv;
    for (int k=0;k<KTOP;k++){
      int bi = 0; float bv = sc[0];
#pragma unroll
      for (int e=1;e<NEXP;e++) if (sc[e] > bv){ bv = sc[e]; bi = e; }
      topw[t*KTOP+k] = bv;           // ROUTE_SCALE == 1
      topi[t*KTOP+k] = bi;
#pragma unroll
      for (int e=0;e<NEXP;e++) if (e == bi) sc[e] = -1.f;   // static-index kill
      atomicAdd(&cnt[bi], 1);
    }
  }
}

// scan + compact work-tile table: tab[i] = (expert<<16)|row_tile, -1 padded.
__global__ void k_scan(const int* __restrict__ cnt, int* __restrict__ off, int* __restrict__ cur,
                       int* __restrict__ tab){
  if (threadIdx.x == 0){
    int a = 0;
    for (int e=0;e<NEXP;e++){ off[e] = a; cur[e] = a; a += cnt[e]; }
    int n = 0;
    for (int e=0;e<NEXP;e++){
      int nt = (cnt[e] + 127) >> 7;
      for (int r=0;r<nt;r++) tab[n++] = (e << 16) | r;
    }
    for (; n < TILEMAX; ++n) tab[n] = -1;
  }
}

__global__ __launch_bounds__(256) void k_place(const int* __restrict__ topi, const float* __restrict__ topw,
                                               int* __restrict__ cur, int* __restrict__ rows,
                                               float* __restrict__ rw, int* __restrict__ slotL){
  int t = blockIdx.x*256 + threadIdx.x;
#pragma unroll
  for (int k=0;k<KTOP;k++){
    int e = topi[t*KTOP+k];
    int p = atomicAdd(&cur[e], 1);
    rows[p] = t;
    rw[p]   = topw[t*KTOP+k];
    slotL[t*KTOP+k] = p;
  }
}

// fp32-weight fallback staging, BK=32 swizzled layout (4 slots/row, XOR (r>>1)&3)
__device__ __forceinline__ void stage_Bf32(unsigned short* lsB, const float* bF,
                                           int bn0, int k0, int tid){
#pragma unroll
  for (int j=0;j<4;j++){
    int idx = j*256 + tid;              // [0,1024): 128 rows x 8 float4
    int r = idx >> 3, c4 = idx & 7;
    float4 v = *(const float4*)(bF + (size_t)(bn0 + r)*DIM + k0 + c4*4);
    uint2 q; q.x = pk2(v.x, v.y); q.y = pk2(v.z, v.w);
    *(uint2*)&lsB[r*32 + (((c4 >> 1) ^ ((r >> 1) & 3)) << 3) + ((c4 & 1) << 2)] = q;
  }
}
// same but generic ldK (for k_gemm fallback)
__device__ __forceinline__ void stage_Bf32K(unsigned short* lsB, const float* bF,
                                            int ldK, int bn0, int k0, int tid){
#pragma unroll
  for (int j=0;j<4;j++){
    int idx = j*256 + tid;
    int r = idx >> 3, c4 = idx & 7;
    float4 v = *(const float4*)(bF + (size_t)(bn0 + r)*ldK + k0 + c4*4);
    uint2 q; q.x = pk2(v.x, v.y); q.y = pk2(v.z, v.w);
    *(uint2*)&lsB[r*32 + (((c4 >> 1) ^ ((r >> 1) & 3)) << 3) + ((c4 & 1) << 2)] = q;
  }
}

// BK=32 fragment read (4 slots/row, involution XOR (r>>1)&3)
__device__ __forceinline__ void read_A32(bf16x8 af[4], const unsigned short* lsA, int wm, int lane){
  int s = lane >> 4;
#pragma unroll
  for (int mi=0;mi<4;mi++){
    int r = wm + mi*16 + (lane & 15);
    af[mi] = *(const bf16x8*)&lsA[r*32 + ((s ^ ((r >> 1) & 3)) << 3)];
  }
}

// ---------------- routed up+gate proj: H1 = silu(A@W1^T+b1)*(A@W3^T+b3), gathered rows ----------------
// 128x128 tile, BK=32, 3-buffer depth-2 counted-vmcnt pipeline (T3/T4):
//   prologue: STAGE(t0), STAGE(t1)                         [12 gll/wave in flight]
//   iter kt : vmcnt(6)  -- tile kt landed, tile kt+1 STAYS IN FLIGHT
//             s_barrier
//             STAGE(tile kt+2 -> set (kt+2)%3)             [set last read at kt-1; barrier proves reads done]
//             32 dual-MFMA on set kt%3
// LDS 3 x (8+8+8)KB = 72KB -> 2 blocks/CU. 6 gll/wave/stage (2 A + 2 B1 + 2 B3).
// Flat grid 2992 = 8 XCD * (11 ct * 34 slots) for per-XCD B-panel L2 reuse.
template<bool WBF>
__global__ __launch_bounds__(256,2) void k_g13(const unsigned short* __restrict__ Xb,
    const void* __restrict__ W1p, const void* __restrict__ W3p,
    const float* __restrict__ b1, const float* __restrict__ b3,
    const int* __restrict__ rows, const int* __restrict__ cnt, const int* __restrict__ offs,
    const int* __restrict__ tab, unsigned short* __restrict__ H1)
{
  int bid = blockIdx.x;
  int l = bid >> 3;
  int ct = l / 34;
  int slot = (bid & 7)*34 + (l - ct*34);
  int ent = tab[slot];
  if (ent < 0) return;
  int e = ent >> 16, rt = ent & 0xffff;
  int cntE = cnt[e];
  int offE = offs[e];
  int hn0 = ct*128;
  int tid = threadIdx.x, lane = tid & 63, wid = tid >> 6;
  int wm = (wid >> 1)*64, wn = (wid & 1)*64;
  __shared__ alignas(16) unsigned short lsA[3][4096], lsB1[3][4096], lsB3[3][4096];

  // staging geometry: round j in {0,1} covers rows r0+j*64; 4 lanes per row (16B each)
  int r0 = tid >> 2;
  int sl = tid & 3;
  int cxg = sl ^ ((r0 >> 1) & 3);     // pre-swizzled source slot (involution of read XOR)
  unsigned offA[2];
#pragma unroll
  for (int j=0;j<2;j++){
    int lrow = rt*128 + r0 + j*64;
    int arow = rows[offE + (lrow < cntE ? lrow : cntE-1)];
    offA[j] = (unsigned)arow*DIM + (unsigned)cxg*8;
  }
  unsigned offB0 = (unsigned)(hn0 + r0)*DIM + (unsigned)cxg*8;   // + j*64*DIM
  const unsigned short* b1H = (const unsigned short*)W1p + (size_t)e*HID*DIM;
  const unsigned short* b3H = (const unsigned short*)W3p + (size_t)e*HID*DIM;
  const float* b1F = (const float*)W1p + (size_t)e*HID*DIM;
  const float* b3F = (const float*)W3p + (size_t)e*HID*DIM;
  unsigned dst0 = (unsigned)tid*8;    // elem offset, + j*2048

  f32x4 acc1[4][4], acc3[4][4];
#pragma unroll
  for (int i=0;i<4;i++)
#pragma unroll
    for (int j=0;j<4;j++){ acc1[i][j] = zero4(); acc3[i][j] = zero4(); }

  auto STAGE = [&](int set, int k0){
#pragma unroll
    for (int j=0;j<2;j++){
      gll16(Xb + offA[j] + k0, &lsA[set][dst0 + j*2048]);
      if constexpr (WBF){
        gll16(b1H + offB0 + j*(64*DIM) + k0, &lsB1[set][dst0 + j*2048]);
        gll16(b3H + offB0 + j*(64*DIM) + k0, &lsB3[set][dst0 + j*2048]);
      }
    }
    if constexpr (!WBF){
      stage_Bf32(lsB1[set], b1F, hn0, k0, tid);
      stage_Bf32(lsB3[set], b3F, hn0, k0, tid);
    }
  };

  constexpr int KS = DIM/32;          // 64
  STAGE(0, 0);
  STAGE(1, 32);
  int cur = 0, stg = 2;
  for (int kt=0; kt<KS; ++kt){
    if (kt+1 < KS) { if constexpr (WBF) WAIT_VM(6); else WAIT_ALL(); }
    else           WAIT_ALL();
    BARRIER();
    if (kt+2 < KS) STAGE(stg, (kt+2)*32);
    bf16x8 af[4]; read_A32(af, lsA[cur], wm, lane);
    int s = lane >> 4;
#pragma unroll
    for (int nj=0;nj<4;nj++){
      int rb = wn + nj*16 + (lane & 15);
      int lof = rb*32 + ((s ^ ((rb >> 1) & 3)) << 3);
      bf16x8 bf1 = *(const bf16x8*)&lsB1[cur][lof];
      bf16x8 bf3 = *(const bf16x8*)&lsB3[cur][lof];
#pragma unroll
      for (int mi=0;mi<4;mi++){
        acc1[mi][nj] = MFMA16(af[mi], bf1, acc1[mi][nj]);
        acc3[mi][nj] = MFMA16(af[mi], bf3, acc3[mi][nj]);
      }
    }
    cur = (cur == 2) ? 0 : cur + 1;
    stg = (stg == 2) ? 0 : stg + 1;
  }
#pragma unroll
  for (int nj=0;nj<4;nj++){
    int h = hn0 + wn + nj*16 + (lane & 15);
    float b1v = b1[e*HID + h];
    float b3v = b3[e*HID + h];
#pragma unroll
    for (int mi=0;mi<4;mi++){
#pragma unroll
      for (int r=0;r<4;r++){
        int gr = rt*128 + wm + mi*16 + (lane >> 4)*4 + r;
        if (gr < cntE){
          float u = acc1[mi][nj][r] + b1v;
          float v = acc3[mi][nj][r] + b3v;
          H1[(size_t)(offE + gr)*HID + h] = f2b(siluf(u)*v);
        }
      }
    }
  }
}

// ---------------- generic single-B GEMM, 128x128 tile, BK=32, 4-buffer depth-3 pipeline ----------------
// vmcnt(8) steady (2 tiles stay in flight), taper 8->4->0 at the tail. LDS 64KB -> 2 blocks/CU.
// MODE 0=gs1(silu->Hs) 1=gs2(store out) 2=g2 atomic 3=g2->Yrows
// MODE>=2: flat grid 4352 = 8 XCD * (16 ct * 34 slots), XCD-chunked.
// MODE<2 : flat grid nct*64, remapped rt=(bid&7)*8+(l&7), ct=l>>3.
template<int MODE, bool WBF, int KSTEPS>
__global__ __launch_bounds__(256,2) void k_gemm(const unsigned short* __restrict__ Abase,
    const void* __restrict__ Bpv, const float* __restrict__ bias,
    float* __restrict__ outF, unsigned short* __restrict__ outH,
    const int* __restrict__ rows, const float* __restrict__ rw,
    const int* __restrict__ cnt, const int* __restrict__ offs,
    const int* __restrict__ tab)
{
  constexpr int KD = KSTEPS*32;
  int e = 0, ct, rt, cntE = 0, offE = 0;
  int bid = blockIdx.x;
  int l = bid >> 3;
  if constexpr (MODE >= 2){
    ct = l / 34;
    int slot = (bid & 7)*34 + (l - ct*34);
    int ent = tab[slot];
    if (ent < 0) return;
    e = ent >> 16; rt = ent & 0xffff;
    cntE = cnt[e];
    offE = offs[e];
  } else {
    rt = (bid & 7)*8 + (l & 7);
    ct = l >> 3;
  }
  int bn0 = ct*128, t0 = rt*128;
  int tid = threadIdx.x, lane = tid & 63, wid = tid >> 6;
  int wm = (wid >> 1)*64, wn = (wid & 1)*64;
  __shared__ alignas(16) unsigned short lsA[4][4096], lsB[4][4096];

  int r0 = tid >> 2;
  int sl = tid & 3;
  int cxg = sl ^ ((r0 >> 1) & 3);
  unsigned offA[2];
#pragma unroll
  for (int j=0;j<2;j++){
    int lrow = t0 + r0 + j*64;
    int arow;
    if constexpr (MODE >= 2) arow = offE + (lrow < cntE ? lrow : cntE-1);
    else                     arow = lrow;
    offA[j] = (unsigned)arow*KD + (unsigned)cxg*8;
  }
  unsigned offB0 = (unsigned)(bn0 + r0)*KD + (unsigned)cxg*8;   // + j*64*KD
  const unsigned short* bH = (const unsigned short*)Bpv + ((MODE >= 2) ? (size_t)e*2048*KD : (size_t)0);
  const float*          bF = (const float*)Bpv          + ((MODE >= 2) ? (size_t)e*2048*KD : (size_t)0);
  const float* biasp = bias + ((MODE >= 2) ? e*DIM : 0);
  unsigned dst0 = (unsigned)tid*8;

  f32x4 acc[4][4];
#pragma unroll
  for (int i=0;i<4;i++)
#pragma unroll
    for (int j=0;j<4;j++) acc[i][j] = zero4();

  auto STAGE = [&](int set, int k0){
#pragma unroll
    for (int j=0;j<2;j++){
      gll16(Abase + offA[j] + k0, &lsA[set][dst0 + j*2048]);
      if constexpr (WBF) gll16(bH + offB0 + j*(64*KD) + k0, &lsB[set][dst0 + j*2048]);
    }
    if constexpr (!WBF) stage_Bf32K(lsB[set], bF, KD, bn0, k0, tid);
  };

  STAGE(0, 0);
  STAGE(1, 32);
  STAGE(2, 64);
  for (int kt=0; kt<KSTEPS; ++kt){
    if constexpr (WBF){
      if      (kt+2 < KSTEPS) WAIT_VM(8);   // tiles kt+1, kt+2 stay in flight
      else if (kt+1 < KSTEPS) WAIT_VM(4);
      else                    WAIT_ALL();
    } else WAIT_ALL();
    BARRIER();
    if (kt+3 < KSTEPS) STAGE((kt+3) & 3, (kt+3)*32);
    int cur = kt & 3;
    bf16x8 af[4]; read_A32(af, lsA[cur], wm, lane);
    int s = lane >> 4;
#pragma unroll
    for (int nj=0;nj<4;nj++){
      int rb = wn + nj*16 + (lane & 15);
      bf16x8 bfr = *(const bf16x8*)&lsB[cur][rb*32 + ((s ^ ((rb >> 1) & 3)) << 3)];
#pragma unroll
      for (int mi=0;mi<4;mi++)
        acc[mi][nj] = MFMA16(af[mi], bfr, acc[mi][nj]);
    }
  }
#pragma unroll
  for (int nj=0;nj<4;nj++){
    int col = bn0 + wn + nj*16 + (lane & 15);
    float bv = biasp[col];
#pragma unroll
    for (int mi=0;mi<4;mi++){
#pragma unroll
      for (int r=0;r<4;r++){
        int lr = wm + mi*16 + (lane >> 4)*4 + r;
        float v = acc[mi][nj][r] + bv;
        if constexpr (MODE == 0){
          outH[(size_t)(t0 + lr)*SHID + col] = f2b(siluf(v));
        } else if constexpr (MODE == 1){
          outF[(size_t)(t0 + lr)*DIM + col] = v;
        } else {
          int gr = t0 + lr;
          if (gr < cntE){
            int slot = offE + gr;
            float wv = rw[slot] * v;
            if constexpr (MODE == 2){
              atomicAdd(outF + (size_t)rows[slot]*DIM + col, wv);
            } else {
              outH[(size_t)slot*DIM + col] = f2b(wv);
            }
          }
        }
      }
    }
  }
}

// ---------------- deterministic combine: out += sum_k Yrows[slot(t,k)] ----------------
__global__ __launch_bounds__(256) void k_comb(const unsigned short* __restrict__ Yr,
                                              const int* __restrict__ slotL, float* __restrict__ out){
  int i = blockIdx.x*256 + threadIdx.x;
  int t = i >> 8, c = i & 255;
  size_t ob = (size_t)t*DIM + (size_t)c*8;
  float4 a = *(float4*)(out + ob);
  float4 b = *(float4*)(out + ob + 4);
  int sl[4];
#pragma unroll
  for (int k=0;k<KTOP;k++) sl[k] = slotL[t*KTOP + k];
#pragma unroll
  for (int k=0;k<KTOP;k++){
    uint4 v = *(const uint4*)(Yr + (size_t)sl[k]*DIM + (size_t)c*8);
    a.x += bu2f(v.x & 0xffffu); a.y += bu2f(v.x >> 16);
    a.z += bu2f(v.y & 0xffffu); a.w += bu2f(v.y >> 16);
    b.x += bu2f(v.z & 0xffffu); b.y += bu2f(v.z >> 16);
    b.z += bu2f(v.w & 0xffffu); b.w += bu2f(v.w >> 16);
  }
  *(float4*)(out + ob) = a;
  *(float4*)(out + ob + 4) = b;
}

// ---------------- host ----------------
extern "C" void kernel_launch(void* const* d_in, const int* in_sizes, int n_in,
                              void* d_out, int out_size, void* d_ws, size_t ws_size,
                              hipStream_t stream)
{
  (void)in_sizes; (void)n_in; (void)out_size;
  const float* emb = (const float*)d_in[0];
  // d_in[1] (x) is shadowed in the reference; unused.
  const float* Wg  = (const float*)d_in[2];
  const float* W1  = (const float*)d_in[3];
  const float* b1  = (const float*)d_in[4];
  const float* W2  = (const float*)d_in[5];
  const float* b2  = (const float*)d_in[6];
  const float* W3  = (const float*)d_in[7];
  const float* b3  = (const float*)d_in[8];
  const float* Ws1 = (const float*)d_in[9];
  const float* bs1 = (const float*)d_in[10];
  const float* Ws2 = (const float*)d_in[11];
  const float* bs2 = (const float*)d_in[12];
  float* out = (float*)d_out;
  char* ws = (char*)d_ws;

  const size_t SZ_XB = (size_t)N_TOK*DIM*2;
  const size_t SZ_H1 = (size_t)N_TOK*KTOP*HID*2;
  const size_t SZ_HS = (size_t)N_TOK*SHID*2;
  const size_t SZ_T4 = (size_t)N_TOK*KTOP*4;
  const size_t SZ_WB = (size_t)NEXP*HID*DIM*2;
  const size_t SZ_SB = (size_t)SHID*DIM*2;
  const size_t SZ_YR = (size_t)N_TOK*KTOP*DIM*2;

  size_t off_xb = 0;
  size_t off_h1 = off_xb + SZ_XB;
  size_t off_hs = off_h1 + SZ_H1;
  size_t off_tw = off_hs + SZ_HS;
  size_t off_ti = off_tw + SZ_T4;
  size_t off_ro = off_ti + SZ_T4;
  size_t off_rw = off_ro + SZ_T4;
  size_t off_sl = off_rw + SZ_T4;
  size_t off_cnt = off_sl + SZ_T4;
  size_t off_off = off_cnt + 256;
  size_t off_cur = off_off + 256;
  size_t off_tab = off_cur + 256;
  size_t base_end = off_tab + TILEMAX*4 + 64;
  size_t off_w1b = base_end;
  size_t off_w3b = off_w1b + SZ_WB;
  size_t off_w2b = off_w3b + SZ_WB;
  size_t off_s1b = off_w2b + SZ_WB;
  size_t off_s2b = off_s1b + SZ_SB;
  size_t wbf_end = off_s2b + SZ_SB;

  bool wbf = ws_size >= wbf_end;                 // bf16 weight cache fits?
  size_t off_yr = wbf ? wbf_end : base_end;
  bool comb = ws_size >= off_yr + SZ_YR;         // deterministic combine path fits?

  unsigned short* Xb = (unsigned short*)(ws + off_xb);
  unsigned short* H1 = (unsigned short*)(ws + off_h1);
  unsigned short* Hs = (unsigned short*)(ws + off_hs);
  float* topw = (float*)(ws + off_tw);
  int*   topi = (int*)(ws + off_ti);
  int*   rowsL= (int*)(ws + off_ro);
  float* rwL  = (float*)(ws + off_rw);
  int*   slotL= (int*)(ws + off_sl);
  int*   cntP = (int*)(ws + off_cnt);
  int*   offP = (int*)(ws + off_off);
  int*   curP = (int*)(ws + off_cur);
  int*   tabP = (int*)(ws + off_tab);
  unsigned short* Yr = (unsigned short*)(ws + off_yr);

  hipMemsetAsync(ws + off_cnt, 0, 768, stream);
  if (wbf){
    k_cvtW<<<4096, 256, 0, stream>>>(W1, W3, W2, Ws1, Ws2,
        (unsigned short*)(ws + off_w1b), (unsigned short*)(ws + off_w3b),
        (unsigned short*)(ws + off_w2b), (unsigned short*)(ws + off_s1b),
        (unsigned short*)(ws + off_s2b));
  }
  k_gate<<<2048, 256, 0, stream>>>(emb, Wg, topw, topi, cntP, Xb);  // also writes Xb (bf16)
  k_scan<<<1, 64, 0, stream>>>(cntP, offP, curP, tabP);
  k_place<<<32, 256, 0, stream>>>(topi, topw, curP, rowsL, rwL, slotL);

  // flat 2992 = 8 XCD * 11 ct * 34 slots
  if (wbf) k_g13<true ><<<2992, 256, 0, stream>>>(Xb, ws+off_w1b, ws+off_w3b, b1, b3, rowsL, cntP, offP, tabP, H1);
  else     k_g13<false><<<2992, 256, 0, stream>>>(Xb, W1, W3, b1, b3, rowsL, cntP, offP, tabP, H1);

  // gs1: N=2816 -> 22 col-tiles of 128; flat 1408; K=2048 -> 64 BK32 steps
  if (wbf) k_gemm<0,true ,64><<<1408, 256, 0, stream>>>(Xb, ws+off_s1b, bs1, nullptr, Hs, nullptr,nullptr,nullptr,nullptr,nullptr);
  else     k_gemm<0,false,64><<<1408, 256, 0, stream>>>(Xb, Ws1, bs1, nullptr, Hs, nullptr,nullptr,nullptr,nullptr,nullptr);

  // gs2: N=2048 -> 16 col-tiles of 128; flat 1024; K=2816 -> 88 steps
  if (wbf) k_gemm<1,true ,88><<<1024, 256, 0, stream>>>(Hs, ws+off_s2b, bs2, out, nullptr, nullptr,nullptr,nullptr,nullptr,nullptr);
  else     k_gemm<1,false,88><<<1024, 256, 0, stream>>>(Hs, Ws2, bs2, out, nullptr, nullptr,nullptr,nullptr,nullptr,nullptr);

  // down-proj: N=2048 -> 16 col-tiles of 128; flat 4352 = 8 XCD * 16 ct * 34 slots; K=1408 -> 44 steps
  if (comb){
    if (wbf) k_gemm<3,true ,44><<<4352, 256, 0, stream>>>(H1, ws+off_w2b, b2, nullptr, Yr, rowsL, rwL, cntP, offP, tabP);
    else     k_gemm<3,false,44><<<4352, 256, 0, stream>>>(H1, W2, b2, nullptr, Yr, rowsL, rwL, cntP, offP, tabP);
    k_comb<<<N_TOK, 256, 0, stream>>>(Yr, slotL, out);
  } else {
    if (wbf) k_gemm<2,true ,44><<<4352, 256, 0, stream>>>(H1, ws+off_w2b, b2, out, nullptr, rowsL, rwL, cntP, offP, tabP);
    else     k_gemm<2,false,44><<<4352, 256, 0, stream>>>(H1, W2, b2, out, nullptr, rowsL, rwL, cntP, offP, tabP);
  }
}

// Round 10
// 1810.635 us; speedup vs baseline: 1.1961x; 1.1961x over previous
//
#include <hip/hip_runtime.h>
#include <stdint.h>

#define N_TOK 8192
#define DIM   2048
#define NEXP  16
#define HID   1408
#define SHID  2816
#define KTOP  4
#define TILEMAX 144   // 256-row tiles: sum ceil(cnt/256) <= 128+16 = 144 = 8*18

typedef __attribute__((ext_vector_type(8))) short bf16x8;
typedef __attribute__((ext_vector_type(4))) float f32x4;

#define MFMA16(a,b,c) __builtin_amdgcn_mfma_f32_16x16x32_bf16((a),(b),(c),0,0,0)

__device__ __forceinline__ unsigned short f2b(float f){
  unsigned u = __float_as_uint(f);
  return (unsigned short)((u + 0x7fffu + ((u >> 16) & 1u)) >> 16);  // RNE bf16
}
__device__ __forceinline__ unsigned pk2(float a, float b){
  return (unsigned)f2b(a) | ((unsigned)f2b(b) << 16);
}
__device__ __forceinline__ float bu2f(unsigned hs){ return __uint_as_float(hs << 16); }
__device__ __forceinline__ float siluf(float x){ return x / (1.f + expf(-x)); }
__device__ __forceinline__ f32x4 zero4(){ f32x4 z; z[0]=0.f; z[1]=0.f; z[2]=0.f; z[3]=0.f; return z; }

// async global->LDS, 16B per lane. LDS dest is wave-uniform base + lane*16 (linear).
__device__ __forceinline__ void gll16(const unsigned short* g, unsigned short* l){
  __builtin_amdgcn_global_load_lds(
      (const __attribute__((address_space(1))) void*)g,
      (__attribute__((address_space(3))) void*)l, 16, 0, 0);
}

// fused 5-tensor weight convert (one launch instead of five)
#define SEGW ((size_t)NEXP*HID*DIM/4)
#define SEGS ((size_t)SHID*DIM/4)
__global__ __launch_bounds__(256) void k_cvtW(const float* __restrict__ W1, const float* __restrict__ W3,
                                              const float* __restrict__ W2, const float* __restrict__ Ws1,
                                              const float* __restrict__ Ws2,
                                              unsigned short* __restrict__ d1, unsigned short* __restrict__ d3,
                                              unsigned short* __restrict__ d2, unsigned short* __restrict__ ds1,
                                              unsigned short* __restrict__ ds2){
  size_t total = 3*SEGW + 2*SEGS;
  for (size_t i = (size_t)blockIdx.x*256 + threadIdx.x; i < total; i += (size_t)gridDim.x*256){
    const float* s; unsigned short* d; size_t off;
    if      (i <   SEGW)        { s = W1;  d = d1;  off = i; }
    else if (i < 2*SEGW)        { s = W3;  d = d3;  off = i - SEGW; }
    else if (i < 3*SEGW)        { s = W2;  d = d2;  off = i - 2*SEGW; }
    else if (i < 3*SEGW + SEGS) { s = Ws1; d = ds1; off = i - 3*SEGW; }
    else                        { s = Ws2; d = ds2; off = i - 3*SEGW - SEGS; }
    float4 v = ((const float4*)s)[off];
    uint2 q; q.x = pk2(v.x, v.y); q.y = pk2(v.z, v.w);
    ((uint2*)d)[off] = q;
  }
}

// ---------------- gate (fused with X->bf16 convert): fp32 logits, softmax, top-4 ----------------
__global__ __launch_bounds__(256) void k_gate(const float* __restrict__ X, const float* __restrict__ Wg,
                                              float* __restrict__ topw, int* __restrict__ topi,
                                              int* __restrict__ cnt, unsigned short* __restrict__ Xb){
  int lane = threadIdx.x & 63;
  int t = blockIdx.x*4 + (threadIdx.x >> 6);
  const float* xr = X + (size_t)t*DIM;
  float4 xv[8];
#pragma unroll
  for (int i=0;i<8;i++){
    xv[i] = *(const float4*)(xr + i*256 + lane*4);
    uint2 q; q.x = pk2(xv[i].x, xv[i].y); q.y = pk2(xv[i].z, xv[i].w);
    *(uint2*)(Xb + (size_t)t*DIM + i*256 + lane*4) = q;   // fused bf16 convert
  }
  float sc[NEXP];
#pragma unroll
  for (int e=0;e<NEXP;e++){
    const float* wr = Wg + e*DIM;
    float s = 0.f;
#pragma unroll
    for (int i=0;i<8;i++){
      float4 w = *(const float4*)(wr + i*256 + lane*4);
      s = fmaf(xv[i].x, w.x, s); s = fmaf(xv[i].y, w.y, s);
      s = fmaf(xv[i].z, w.z, s); s = fmaf(xv[i].w, w.w, s);
    }
#pragma unroll
    for (int d=1; d<64; d<<=1) s += __shfl_xor(s, d);
    sc[e] = s;
  }
  if (lane == 0){
    float m = sc[0];
#pragma unroll
    for (int e=1;e<NEXP;e++) m = fmaxf(m, sc[e]);
    float den = 0.f;
#pragma unroll
    for (int e=0;e<NEXP;e++){ sc[e] = expf(sc[e]-m); den += sc[e]; }
    float inv = 1.f/den;
#pragma unroll
    for (int e=0;e<NEXP;e++) sc[e] *= inv;
    for (int k=0;k<KTOP;k++){
      int bi = 0; float bv = sc[0];
#pragma unroll
      for (int e=1;e<NEXP;e++) if (sc[e] > bv){ bv = sc[e]; bi = e; }
      topw[t*KTOP+k] = bv;           // ROUTE_SCALE == 1
      topi[t*KTOP+k] = bi;
#pragma unroll
      for (int e=0;e<NEXP;e++) if (e == bi) sc[e] = -1.f;   // static-index kill
      atomicAdd(&cnt[bi], 1);
    }
  }
}

// scan + compact 256-row work-tile table: tab[i] = (expert<<16)|row_tile, -1 padded.
__global__ void k_scan(const int* __restrict__ cnt, int* __restrict__ off, int* __restrict__ cur,
                       int* __restrict__ tab){
  if (threadIdx.x == 0){
    int a = 0;
    for (int e=0;e<NEXP;e++){ off[e] = a; cur[e] = a; a += cnt[e]; }
    int n = 0;
    for (int e=0;e<NEXP;e++){
      int nt = (cnt[e] + 255) >> 8;
      for (int r=0;r<nt;r++) tab[n++] = (e << 16) | r;
    }
    for (; n < TILEMAX; ++n) tab[n] = -1;
  }
}

__global__ __launch_bounds__(256) void k_place(const int* __restrict__ topi, const float* __restrict__ topw,
                                               int* __restrict__ cur, int* __restrict__ rows,
                                               float* __restrict__ rw, int* __restrict__ slotL){
  int t = blockIdx.x*256 + threadIdx.x;
#pragma unroll
  for (int k=0;k<KTOP;k++){
    int e = topi[t*KTOP+k];
    int p = atomicAdd(&cur[e], 1);
    rows[p] = t;
    rw[p]   = topw[t*KTOP+k];
    slotL[t*KTOP+k] = p;
  }
}

// fp32-weight fallback staging, 512 threads, BK=64 swizzled layout (8 slots/row, XOR r&7)
__device__ __forceinline__ void stage_Bf512(unsigned short* lsB, const float* bF,
                                            int ldK, int bn0, int k0, int tid){
#pragma unroll
  for (int j=0;j<4;j++){
    int idx = j*512 + tid, r = idx >> 4, c4 = idx & 15;
    float4 v = *(const float4*)(bF + (size_t)(bn0 + r)*ldK + k0 + c4*4);
    uint2 q; q.x = pk2(v.x, v.y); q.y = pk2(v.z, v.w);
    *(uint2*)&lsB[r*64 + (((c4 >> 1) ^ (r & 7)) << 3) + ((c4 & 1) << 2)] = q;
  }
}

// BK=64 fragment read (8 slots/row, involution XOR r&7). r may span [0,256).
__device__ __forceinline__ void read_A(bf16x8 af[4], const unsigned short* lsA, int wm, int lane, int kc){
  int s = kc*4 + (lane >> 4);
#pragma unroll
  for (int mi=0;mi<4;mi++){
    int r = wm + mi*16 + (lane & 15);
    af[mi] = *(const bf16x8*)&lsA[r*64 + ((s ^ (r & 7)) << 3)];
  }
}

// ---------------- routed up+gate proj: H1 = silu(A@W1^T+b1)*(A@W3^T+b3), gathered rows ----------------
// BM=256 x BN=128 x BK=64, 512 threads (8 waves, 64x64 out each), single-buffer 2-barrier.
// Key change vs r6: B1/B3 panels staged once per 256 rows (was 128) -> B staging traffic halved;
// staging-byte roofline was the measured bound (r5/r7/r9 schedule-null at fixed bytes).
// Flat grid 1584 = 8 XCD * (11 ct * 18 slots): per-XCD B-panel L2 reuse, ct-major order.
template<bool WBF>
__global__ __launch_bounds__(512,2) void k_g13(const unsigned short* __restrict__ Xb,
    const void* __restrict__ W1p, const void* __restrict__ W3p,
    const float* __restrict__ b1, const float* __restrict__ b3,
    const int* __restrict__ rows, const int* __restrict__ cnt, const int* __restrict__ offs,
    const int* __restrict__ tab, unsigned short* __restrict__ H1)
{
  int bid = blockIdx.x;
  int l = bid >> 3;
  int ct = l / 18;
  int slot = (bid & 7)*18 + (l - ct*18);
  int ent = tab[slot];
  if (ent < 0) return;
  int e = ent >> 16, rt = ent & 0xffff;
  int cntE = cnt[e];
  int offE = offs[e];
  int hn0 = ct*128;
  int tid = threadIdx.x, lane = tid & 63, wid = tid >> 6;   // wid in [0,8)
  int wm = (wid >> 1)*64, wn = (wid & 1)*64;                // 4M x 2N wave grid
  __shared__ alignas(16) unsigned short lsA[16384], lsB1[8192], lsB3[8192];  // 32+16+16 KB

  int r0 = tid >> 3;                  // [0,64): row within 64-row staging group
  int cx = (tid & 7) ^ (r0 & 7);      // pre-swizzled source k-chunk (involution of read XOR)
  unsigned offA[4];
#pragma unroll
  for (int j=0;j<4;j++){
    int lrow = rt*256 + j*64 + r0;
    int arow = rows[offE + (lrow < cntE ? lrow : cntE-1)];
    offA[j] = (unsigned)arow*DIM + (unsigned)cx*8;
  }
  unsigned offB0 = (unsigned)(hn0 + r0)*DIM + (unsigned)cx*8;   // + j*64*DIM, j<2
  const unsigned short* b1H = (const unsigned short*)W1p + (size_t)e*HID*DIM;
  const unsigned short* b3H = (const unsigned short*)W3p + (size_t)e*HID*DIM;
  const float* b1F = (const float*)W1p + (size_t)e*HID*DIM;
  const float* b3F = (const float*)W3p + (size_t)e*HID*DIM;
  unsigned dst0 = (unsigned)tid*8;    // elem offset; + j*4096

  f32x4 acc1[4][4], acc3[4][4];
#pragma unroll
  for (int i=0;i<4;i++)
#pragma unroll
    for (int j=0;j<4;j++){ acc1[i][j] = zero4(); acc3[i][j] = zero4(); }

  for (int kt=0; kt<DIM/64; ++kt){
    int k0 = kt*64;
    __syncthreads();
#pragma unroll
    for (int j=0;j<4;j++) gll16(Xb + offA[j] + k0, &lsA[dst0 + j*4096]);
    if constexpr (WBF){
#pragma unroll
      for (int j=0;j<2;j++){
        gll16(b1H + offB0 + j*(64*DIM) + k0, &lsB1[dst0 + j*4096]);
        gll16(b3H + offB0 + j*(64*DIM) + k0, &lsB3[dst0 + j*4096]);
      }
    } else {
      stage_Bf512(lsB1, b1F, DIM, hn0, k0, tid);
      stage_Bf512(lsB3, b3F, DIM, hn0, k0, tid);
    }
    __syncthreads();   // drains vmcnt/lgkmcnt -> staged data visible
#pragma unroll
    for (int kc=0;kc<2;kc++){
      bf16x8 af[4]; read_A(af, lsA, wm, lane, kc);
      int sB = kc*4 + (lane >> 4);
#pragma unroll
      for (int nj=0;nj<4;nj++){
        int rb = wn + nj*16 + (lane & 15);
        int lof = rb*64 + ((sB ^ (rb & 7)) << 3);
        bf16x8 bf1 = *(const bf16x8*)&lsB1[lof];
        bf16x8 bf3 = *(const bf16x8*)&lsB3[lof];
#pragma unroll
        for (int mi=0;mi<4;mi++){
          acc1[mi][nj] = MFMA16(af[mi], bf1, acc1[mi][nj]);
          acc3[mi][nj] = MFMA16(af[mi], bf3, acc3[mi][nj]);
        }
      }
    }
  }
#pragma unroll
  for (int nj=0;nj<4;nj++){
    int h = hn0 + wn + nj*16 + (lane & 15);
    float b1v = b1[e*HID + h];
    float b3v = b3[e*HID + h];
#pragma unroll
    for (int mi=0;mi<4;mi++){
#pragma unroll
      for (int r=0;r<4;r++){
        int gr = rt*256 + wm + mi*16 + (lane >> 4)*4 + r;
        if (gr < cntE){
          float u = acc1[mi][nj][r] + b1v;
          float v = acc3[mi][nj][r] + b3v;
          H1[(size_t)(offE + gr)*HID + h] = f2b(siluf(u)*v);
        }
      }
    }
  }
}

// ---------------- generic single-B GEMM, BM=256 x BN=128 x BK=64, 512 threads, 2-barrier ----------------
// MODE 0=gs1(silu->Hs) 1=gs2(store out) 2=g2 atomic 3=g2->Yrows
// MODE>=2: flat grid 2304 = 8 XCD * (16 ct * 18 slots), XCD-chunked, A rows contiguous slots.
// MODE<2 : flat grid 8*(nct*4): rt=(bid&7)*4+(l&3), ct=l>>2 (per-XCD rt chunk).
template<int MODE, bool WBF, int KSTEPS>
__global__ __launch_bounds__(512,2) void k_gemm(const unsigned short* __restrict__ Abase,
    const void* __restrict__ Bpv, const float* __restrict__ bias,
    float* __restrict__ outF, unsigned short* __restrict__ outH,
    const int* __restrict__ rows, const float* __restrict__ rw,
    const int* __restrict__ cnt, const int* __restrict__ offs,
    const int* __restrict__ tab)
{
  constexpr int KD = KSTEPS*64;
  int e = 0, ct, rt, cntE = 0, offE = 0;
  int bid = blockIdx.x;
  int l = bid >> 3;
  if constexpr (MODE >= 2){
    ct = l / 18;
    int slot = (bid & 7)*18 + (l - ct*18);
    int ent = tab[slot];
    if (ent < 0) return;
    e = ent >> 16; rt = ent & 0xffff;
    cntE = cnt[e];
    offE = offs[e];
  } else {
    rt = (bid & 7)*4 + (l & 3);
    ct = l >> 2;
  }
  int bn0 = ct*128, t0 = rt*256;
  int tid = threadIdx.x, lane = tid & 63, wid = tid >> 6;
  int wm = (wid >> 1)*64, wn = (wid & 1)*64;
  __shared__ alignas(16) unsigned short lsA[16384], lsB[8192];   // 32+16 KB

  int r0 = tid >> 3;
  int cx = (tid & 7) ^ (r0 & 7);
  unsigned offA[4];
#pragma unroll
  for (int j=0;j<4;j++){
    int lrow = t0 + j*64 + r0;
    int arow;
    if constexpr (MODE >= 2) arow = offE + (lrow < cntE ? lrow : cntE-1);
    else                     arow = lrow;
    offA[j] = (unsigned)arow*KD + (unsigned)cx*8;
  }
  unsigned offB0 = (unsigned)(bn0 + r0)*KD + (unsigned)cx*8;   // + j*64*KD, j<2
  const unsigned short* bH = (const unsigned short*)Bpv + ((MODE >= 2) ? (size_t)e*2048*KD : (size_t)0);
  const float*          bF = (const float*)Bpv          + ((MODE >= 2) ? (size_t)e*2048*KD : (size_t)0);
  const float* biasp = bias + ((MODE >= 2) ? e*DIM : 0);
  unsigned dst0 = (unsigned)tid*8;

  f32x4 acc[4][4];
#pragma unroll
  for (int i=0;i<4;i++)
#pragma unroll
    for (int j=0;j<4;j++) acc[i][j] = zero4();

  for (int kt=0; kt<KSTEPS; ++kt){
    int k0 = kt*64;
    __syncthreads();
#pragma unroll
    for (int j=0;j<4;j++) gll16(Abase + offA[j] + k0, &lsA[dst0 + j*4096]);
    if constexpr (WBF){
#pragma unroll
      for (int j=0;j<2;j++) gll16(bH + offB0 + j*(64*KD) + k0, &lsB[dst0 + j*4096]);
    } else {
      stage_Bf512(lsB, bF, KD, bn0, k0, tid);
    }
    __syncthreads();
#pragma unroll
    for (int kc=0;kc<2;kc++){
      bf16x8 af[4]; read_A(af, lsA, wm, lane, kc);
      int sB = kc*4 + (lane >> 4);
#pragma unroll
      for (int nj=0;nj<4;nj++){
        int rb = wn + nj*16 + (lane & 15);
        bf16x8 bfr = *(const bf16x8*)&lsB[rb*64 + ((sB ^ (rb & 7)) << 3)];
#pragma unroll
        for (int mi=0;mi<4;mi++)
          acc[mi][nj] = MFMA16(af[mi], bfr, acc[mi][nj]);
      }
    }
  }
#pragma unroll
  for (int nj=0;nj<4;nj++){
    int col = bn0 + wn + nj*16 + (lane & 15);
    float bv = biasp[col];
#pragma unroll
    for (int mi=0;mi<4;mi++){
#pragma unroll
      for (int r=0;r<4;r++){
        int lr = wm + mi*16 + (lane >> 4)*4 + r;
        float v = acc[mi][nj][r] + bv;
        if constexpr (MODE == 0){
          outH[(size_t)(t0 + lr)*SHID + col] = f2b(siluf(v));
        } else if constexpr (MODE == 1){
          outF[(size_t)(t0 + lr)*DIM + col] = v;
        } else {
          int gr = t0 + lr;
          if (gr < cntE){
            int slot = offE + gr;
            float wv = rw[slot] * v;
            if constexpr (MODE == 2){
              atomicAdd(outF + (size_t)rows[slot]*DIM + col, wv);
            } else {
              outH[(size_t)slot*DIM + col] = f2b(wv);
            }
          }
        }
      }
    }
  }
}

// ---------------- deterministic combine: out += sum_k Yrows[slot(t,k)] ----------------
__global__ __launch_bounds__(256) void k_comb(const unsigned short* __restrict__ Yr,
                                              const int* __restrict__ slotL, float* __restrict__ out){
  int i = blockIdx.x*256 + threadIdx.x;
  int t = i >> 8, c = i & 255;
  size_t ob = (size_t)t*DIM + (size_t)c*8;
  float4 a = *(float4*)(out + ob);
  float4 b = *(float4*)(out + ob + 4);
  int sl[4];
#pragma unroll
  for (int k=0;k<KTOP;k++) sl[k] = slotL[t*KTOP + k];
#pragma unroll
  for (int k=0;k<KTOP;k++){
    uint4 v = *(const uint4*)(Yr + (size_t)sl[k]*DIM + (size_t)c*8);
    a.x += bu2f(v.x & 0xffffu); a.y += bu2f(v.x >> 16);
    a.z += bu2f(v.y & 0xffffu); a.w += bu2f(v.y >> 16);
    b.x += bu2f(v.z & 0xffffu); b.y += bu2f(v.z >> 16);
    b.z += bu2f(v.w & 0xffffu); b.w += bu2f(v.w >> 16);
  }
  *(float4*)(out + ob) = a;
  *(float4*)(out + ob + 4) = b;
}

// ---------------- host ----------------
extern "C" void kernel_launch(void* const* d_in, const int* in_sizes, int n_in,
                              void* d_out, int out_size, void* d_ws, size_t ws_size,
                              hipStream_t stream)
{
  (void)in_sizes; (void)n_in; (void)out_size;
  const float* emb = (const float*)d_in[0];
  // d_in[1] (x) is shadowed in the reference; unused.
  const float* Wg  = (const float*)d_in[2];
  const float* W1  = (const float*)d_in[3];
  const float* b1  = (const float*)d_in[4];
  const float* W2  = (const float*)d_in[5];
  const float* b2  = (const float*)d_in[6];
  const float* W3  = (const float*)d_in[7];
  const float* b3  = (const float*)d_in[8];
  const float* Ws1 = (const float*)d_in[9];
  const float* bs1 = (const float*)d_in[10];
  const float* Ws2 = (const float*)d_in[11];
  const float* bs2 = (const float*)d_in[12];
  float* out = (float*)d_out;
  char* ws = (char*)d_ws;

  const size_t SZ_XB = (size_t)N_TOK*DIM*2;
  const size_t SZ_H1 = (size_t)N_TOK*KTOP*HID*2;
  const size_t SZ_HS = (size_t)N_TOK*SHID*2;
  const size_t SZ_T4 = (size_t)N_TOK*KTOP*4;
  const size_t SZ_WB = (size_t)NEXP*HID*DIM*2;
  const size_t SZ_SB = (size_t)SHID*DIM*2;
  const size_t SZ_YR = (size_t)N_TOK*KTOP*DIM*2;

  size_t off_xb = 0;
  size_t off_h1 = off_xb + SZ_XB;
  size_t off_hs = off_h1 + SZ_H1;
  size_t off_tw = off_hs + SZ_HS;
  size_t off_ti = off_tw + SZ_T4;
  size_t off_ro = off_ti + SZ_T4;
  size_t off_rw = off_ro + SZ_T4;
  size_t off_sl = off_rw + SZ_T4;
  size_t off_cnt = off_sl + SZ_T4;
  size_t off_off = off_cnt + 256;
  size_t off_cur = off_off + 256;
  size_t off_tab = off_cur + 256;
  size_t base_end = off_tab + TILEMAX*4 + 64;
  size_t off_w1b = base_end;
  size_t off_w3b = off_w1b + SZ_WB;
  size_t off_w2b = off_w3b + SZ_WB;
  size_t off_s1b = off_w2b + SZ_WB;
  size_t off_s2b = off_s1b + SZ_SB;
  size_t wbf_end = off_s2b + SZ_SB;

  bool wbf = ws_size >= wbf_end;                 // bf16 weight cache fits?
  size_t off_yr = wbf ? wbf_end : base_end;
  bool comb = ws_size >= off_yr + SZ_YR;         // deterministic combine path fits?

  unsigned short* Xb = (unsigned short*)(ws + off_xb);
  unsigned short* H1 = (unsigned short*)(ws + off_h1);
  unsigned short* Hs = (unsigned short*)(ws + off_hs);
  float* topw = (float*)(ws + off_tw);
  int*   topi = (int*)(ws + off_ti);
  int*   rowsL= (int*)(ws + off_ro);
  float* rwL  = (float*)(ws + off_rw);
  int*   slotL= (int*)(ws + off_sl);
  int*   cntP = (int*)(ws + off_cnt);
  int*   offP = (int*)(ws + off_off);
  int*   curP = (int*)(ws + off_cur);
  int*   tabP = (int*)(ws + off_tab);
  unsigned short* Yr = (unsigned short*)(ws + off_yr);

  hipMemsetAsync(ws + off_cnt, 0, 768, stream);
  if (wbf){
    k_cvtW<<<4096, 256, 0, stream>>>(W1, W3, W2, Ws1, Ws2,
        (unsigned short*)(ws + off_w1b), (unsigned short*)(ws + off_w3b),
        (unsigned short*)(ws + off_w2b), (unsigned short*)(ws + off_s1b),
        (unsigned short*)(ws + off_s2b));
  }
  k_gate<<<2048, 256, 0, stream>>>(emb, Wg, topw, topi, cntP, Xb);  // also writes Xb (bf16)
  k_scan<<<1, 64, 0, stream>>>(cntP, offP, curP, tabP);
  k_place<<<32, 256, 0, stream>>>(topi, topw, curP, rowsL, rwL, slotL);

  // flat 1584 = 8 XCD * 11 ct * 18 slots (256-row tiles)
  if (wbf) k_g13<true ><<<1584, 512, 0, stream>>>(Xb, ws+off_w1b, ws+off_w3b, b1, b3, rowsL, cntP, offP, tabP, H1);
  else     k_g13<false><<<1584, 512, 0, stream>>>(Xb, W1, W3, b1, b3, rowsL, cntP, offP, tabP, H1);

  // gs1: M=8192/256=32 rt, N=2816/128=22 ct; flat 704 = 8*(22*4); K=2048 -> 32 steps
  if (wbf) k_gemm<0,true ,32><<<704, 512, 0, stream>>>(Xb, ws+off_s1b, bs1, nullptr, Hs, nullptr,nullptr,nullptr,nullptr,nullptr);
  else     k_gemm<0,false,32><<<704, 512, 0, stream>>>(Xb, Ws1, bs1, nullptr, Hs, nullptr,nullptr,nullptr,nullptr,nullptr);

  // gs2: 32 rt x 16 ct; flat 512 = 8*(16*4); K=2816 -> 44 steps
  if (wbf) k_gemm<1,true ,44><<<512, 512, 0, stream>>>(Hs, ws+off_s2b, bs2, out, nullptr, nullptr,nullptr,nullptr,nullptr,nullptr);
  else     k_gemm<1,false,44><<<512, 512, 0, stream>>>(Hs, Ws2, bs2, out, nullptr, nullptr,nullptr,nullptr,nullptr,nullptr);

  // down-proj: flat 2304 = 8 XCD * 16 ct * 18 slots; K=1408 -> 22 steps
  if (comb){
    if (wbf) k_gemm<3,true ,22><<<2304, 512, 0, stream>>>(H1, ws+off_w2b, b2, nullptr, Yr, rowsL, rwL, cntP, offP, tabP);
    else     k_gemm<3,false,22><<<2304, 512, 0, stream>>>(H1, W2, b2, nullptr, Yr, rowsL, rwL, cntP, offP, tabP);
    k_comb<<<N_TOK, 256, 0, stream>>>(Yr, slotL, out);
  } else {
    if (wbf) k_gemm<2,true ,22><<<2304, 512, 0, stream>>>(H1, ws+off_w2b, b2, out, nullptr, rowsL, rwL, cntP, offP, tabP);
    else     k_gemm<2,false,22><<<2304, 512, 0, stream>>>(H1, W2, b2, out, nullptr, rowsL, rwL, cntP, offP, tabP);
  }
}